// Round 5
// baseline (6499.570 us; speedup 1.0000x reference)
//
#include <hip/hip_runtime.h>

// ---------------- problem dims ----------------
#define BATCH 64
#define SEQ   512
#define HID   512
#define DPRIM 64
#define DAUX  32
#define CT    16
#define NCHUNK 32
#define NBAT  32          // batches per WG
#define WP    520         // u16 pitch, 512-wide rows (GEMM B-tile)
#define XPI   104         // u16 pitch, 96-wide rows
#define PST   33

// ---------------- ws byte offsets ----------------
#define WS_HB0HI  0u
#define WS_HB0LO  131072u
#define WS_HB1HI  262144u
#define WS_HB1LO  393216u
#define WS_SLOT0  524288u
#define WS_SLOT1  526336u
#define WS_GDONE  528384u
#define WS_XPD    530432u
#define WS_STATE_END 532480u
#define WS_PHH0HI 532480u
#define WS_PHH0LO 2629632u
#define WS_PHH1HI 4726784u
#define WS_PHH1LO 6823936u
#define WS_PIH1HI 8921088u
#define WS_PIH1LO 11018240u
#define WS_PIH0HI 13115392u
#define WS_PIH0LO 13508608u
#define WS_BSUM0  13901824u
#define WS_BSUM1  13910016u
#define WS_WOT    13918208u
#define WS_HIST   14180352u   // u32[2][64][CT][512]
#define WS_XP0    18374656u   // f32[128][16384]
#define WS_XP1    26763264u   // f32[128][16384]

typedef short s16x8 __attribute__((ext_vector_type(8)));
typedef float f32x4 __attribute__((ext_vector_type(4)));
typedef unsigned long long u64x2 __attribute__((ext_vector_type(2)));
typedef unsigned long long u64t;
typedef unsigned int u32t;
typedef unsigned short u16t;

__device__ __forceinline__ float sigm(float x)  { return 1.f / (1.f + __expf(-x)); }
__device__ __forceinline__ float tanh_f(float x){ return 1.f - 2.f / (__expf(2.f * x) + 1.f); }
__device__ __forceinline__ u16t f2b(float f) {
    u32t u = __float_as_uint(f);
    u += 0x7fffu + ((u >> 16) & 1u);
    return (u16t)(u >> 16);
}
__device__ __forceinline__ void split2(float f, u16t* hi, u16t* lo) {
    u16t h = f2b(f);
    float r = f - __uint_as_float((u32t)h << 16);
    *hi = h; *lo = f2b(r);
}
__device__ __forceinline__ s16x8 mk_s16x8(u64t a, u64t b) {
    u64x2 t; t.x = a; t.y = b;
    return __builtin_bit_cast(s16x8, t);
}
// coherent (cross-XCD, sc1/MALL) access — proven R2-R4
__device__ __forceinline__ u64t ld_coh64(const u64t* p) {
    return __hip_atomic_load(p, __ATOMIC_RELAXED, __HIP_MEMORY_SCOPE_AGENT);
}
__device__ __forceinline__ float ld_cohf(const float* p) {
    return __hip_atomic_load(p, __ATOMIC_RELAXED, __HIP_MEMORY_SCOPE_AGENT);
}
__device__ __forceinline__ void st_coh64w(u64t* p, u64t v) {
    __hip_atomic_store(p, v, __ATOMIC_RELAXED, __HIP_MEMORY_SCOPE_AGENT);
}
__device__ __forceinline__ void st_cohf(float* p, float v) {
    __hip_atomic_store(p, v, __ATOMIC_RELAXED, __HIP_MEMORY_SCOPE_AGENT);
}
__device__ __forceinline__ int ld_slot(const int* p) {
    return __hip_atomic_load(p, __ATOMIC_RELAXED, __HIP_MEMORY_SCOPE_AGENT);
}
__device__ __forceinline__ void st_slot(int* p, int v) {
    __hip_atomic_store(p, v, __ATOMIC_RELAXED, __HIP_MEMORY_SCOPE_AGENT);
}
#define MFMA16(a,b,c) __builtin_amdgcn_mfma_f32_16x16x32_bf16(a,b,c,0,0,0)

// load per-wave recurrent-weight fragments into registers (plain cached loads)
__device__ __forceinline__ void load_afrag(const u16t* ph, const u16t* pl,
                                           int u0, int col, int kg, int rt, int kh,
                                           s16x8* ah, s16x8* al) {
    int r = rt * 16 + col;
    int grow = (r >> 3) * HID + u0 + (r & 7);
    const u16t* sh = ph + (size_t)grow * HID;
    const u16t* sl = pl + (size_t)grow * HID;
#pragma unroll
    for (int k2 = 0; k2 < 8; ++k2) {
        int ko = (kh * 8 + k2) * 32 + kg * 8;
        ah[k2] = *(const s16x8*)(sh + ko);
        al[k2] = *(const s16x8*)(sl + ko);
    }
}

// =====================================================================
// prep: split all weights to hi/lo bf16 planes; bias sums; W_out^T
// =====================================================================
__global__ void prep_kernel(const float* __restrict__ Wih0, const float* __restrict__ Whh0,
                            const float* __restrict__ bih0, const float* __restrict__ bhh0,
                            const float* __restrict__ Wih1, const float* __restrict__ Whh1,
                            const float* __restrict__ bih1, const float* __restrict__ bhh1,
                            const float* __restrict__ Wout, char* __restrict__ ws)
{
    int idx = blockIdx.x * 256 + threadIdx.x;          // 0..1048575
    u16t h, l;
    split2(Whh0[idx], &h, &l);
    ((u16t*)(ws + WS_PHH0HI))[idx] = h; ((u16t*)(ws + WS_PHH0LO))[idx] = l;
    split2(Whh1[idx], &h, &l);
    ((u16t*)(ws + WS_PHH1HI))[idx] = h; ((u16t*)(ws + WS_PHH1LO))[idx] = l;
    split2(Wih1[idx], &h, &l);
    ((u16t*)(ws + WS_PIH1HI))[idx] = h; ((u16t*)(ws + WS_PIH1LO))[idx] = l;
    if (idx < 2048 * 96) {
        split2(Wih0[idx], &h, &l);
        ((u16t*)(ws + WS_PIH0HI))[idx] = h; ((u16t*)(ws + WS_PIH0LO))[idx] = l;
    }
    if (idx < 2048) {
        ((float*)(ws + WS_BSUM0))[idx] = bih0[idx] + bhh0[idx];
        ((float*)(ws + WS_BSUM1))[idx] = bih1[idx] + bhh1[idx];
    }
    if (idx < 65536) {
        ((float*)(ws + WS_WOT))[idx] = Wout[(size_t)(idx & 127) * HID + (idx >> 7)];
    }
}

// =====================================================================
// one recurrent step: reg-A, direct-global-B (no LDS staging)
// wave role: rt=(wid>>1)&1 rows, bt=wid&1 batches, kh=wid>>2 K-half
// =====================================================================
__device__ __forceinline__ void do_step(
    int t, int c, int tl, int tid, int col, int kg,
    int rt, int bt, int kh,
    int b0, int u0, int ug,
    const s16x8* ah, const s16x8* al,
    float* Ps, float* Cs,
    u16t* hbhi, u16t* hblo, int* slots_self,
    const float* xp_self, bool coh_xq, u32t* hist_ring)
{
    const int p = t & 1;
    // xq prefetch (chunk-static) — overlaps the poll
    float xq0 = 0.f, xq1 = 0.f, xq2 = 0.f, xq3 = 0.f;
    if (tid < 256) {
        int b = tid >> 3, u = tid & 7;
        const float* xr = xp_self + (size_t)(b * CT + tl) * 32;
        if (coh_xq) {
            xq0 = ld_cohf(xr + u);      xq1 = ld_cohf(xr + 8 + u);
            xq2 = ld_cohf(xr + 16 + u); xq3 = ld_cohf(xr + 24 + u);
        } else {
            xq0 = xr[u]; xq1 = xr[8 + u]; xq2 = xr[16 + u]; xq3 = xr[24 + u];
        }
    }
    // per-wave poll: only this wave's K-half producers (32 slots)
    {
        int lane = tid & 63;
        const int* sp = slots_self + (kh * 32 + (lane & 31)) * 4;
        while (true) {
            int v = (lane < 32) ? ld_slot(sp) : 0x7fffffff;
            if (__all(v >= t)) break;
            __builtin_amdgcn_s_sleep(1);
        }
    }
    asm volatile("" ::: "memory");    // forbid hoisting B loads above the poll
    // B fragments straight from coherent h planes (no LDS)
    const size_t brow = (size_t)((p ^ 1) * BATCH + b0 + bt * 16 + col) * HID;
    s16x8 bh[8], bl[8];
#pragma unroll
    for (int k2 = 0; k2 < 8; ++k2) {
        int ko = (kh * 8 + k2) * 32 + kg * 8;
        u64t h0 = ld_coh64((const u64t*)(hbhi + brow + ko));
        u64t h1 = ld_coh64((const u64t*)(hbhi + brow + ko + 4));
        u64t l0 = ld_coh64((const u64t*)(hblo + brow + ko));
        u64t l1 = ld_coh64((const u64t*)(hblo + brow + ko + 4));
        bh[k2] = mk_s16x8(h0, h1);
        bl[k2] = mk_s16x8(l0, l1);
    }
    f32x4 a0 = {0.f, 0.f, 0.f, 0.f}, a1 = {0.f, 0.f, 0.f, 0.f};
#pragma unroll
    for (int k2 = 0; k2 < 8; ++k2) {
        a0 = MFMA16(ah[k2], bh[k2], a0);
        a1 = MFMA16(ah[k2], bl[k2], a1);
        a0 = MFMA16(al[k2], bh[k2], a0);
    }
    a0 = a0 + a1;
#pragma unroll
    for (int j = 0; j < 4; ++j)
        Ps[((kh << 5) + rt * 16 + kg * 4 + j) * PST + bt * 16 + col] = a0[j];
    __syncthreads();
    // activations + state + packed coherent publish
    if (tid < 256) {
        int b = tid >> 3, u = tid & 7;
        float gi = Ps[(u)      * PST + b] + Ps[(32 + u) * PST + b] + xq0;
        float gf = Ps[(8 + u)  * PST + b] + Ps[(40 + u) * PST + b] + xq1;
        float gg = Ps[(16 + u) * PST + b] + Ps[(48 + u) * PST + b] + xq2;
        float go = Ps[(24 + u) * PST + b] + Ps[(56 + u) * PST + b] + xq3;
        float si = sigm(gi), sf = sigm(gf), so = sigm(go);
        float tg = tanh_f(gg);
        float cN = sf * Cs[tid] + si * tg;
        Cs[tid] = cN;
        float hN = so * tanh_f(cN);
        u16t hi, lo; split2(hN, &hi, &lo);
        u32t wh = (u32t)hi | (((u32t)(u16t)__shfl_xor((int)hi, 1)) << 16);
        u32t wl = (u32t)lo | (((u32t)(u16t)__shfl_xor((int)lo, 1)) << 16);
        u64t qh = (u64t)wh | ((u64t)(u32t)__shfl_xor((int)wh, 2) << 32);
        u64t ql = (u64t)wl | ((u64t)(u32t)__shfl_xor((int)wl, 2) << 32);
        size_t e = ((size_t)p * BATCH + b0 + b) * HID + u0 + u;
        if ((u & 3) == 0) {
            st_coh64w((u64t*)hbhi + (e >> 2), qh);
            st_coh64w((u64t*)hblo + (e >> 2), ql);
        }
        if (hist_ring) {
            u32t pk = ((u32t)hi << 16) | (u32t)lo;
            u64t qp = (u64t)pk | ((u64t)(u32t)__shfl_xor((int)pk, 1) << 32);
            if ((u & 1) == 0)
                st_coh64w((u64t*)(hist_ring +
                    ((size_t)((c & 1) * BATCH + b0 + b) * CT + tl) * HID + u0 + u), qp);
        }
    }
    __syncthreads();   // drains vmcnt: publishes globally visible
    if (tid == 0) st_slot(slots_self + ug * 4, t + 1);
}

// =====================================================================
// mega kernel: 256 WGs resident. WG 0..127 = layer0, 128..255 = layer1.
// =====================================================================
__global__ __launch_bounds__(512, 2)
void mega_kernel(const float* __restrict__ prim, const float* __restrict__ aux,
                 char* __restrict__ ws)
{
    __shared__ __align__(16) unsigned char smem[156032];
    u16t* Bthi = (u16t*)smem;                       // 66560  (layer1 GEMM B-tile)
    u16t* Btlo = (u16t*)(smem + 66560);             // 66560
    u16t* XWhi = (u16t*)(smem + 133120);            // 6656   (layer0)
    u16t* XWlo = (u16t*)(smem + 139776);            // 6656
    float* Ps  = (float*)(smem + 146432);           // 8448   [64][PST]
    float* Cs  = (float*)(smem + 154880);           // 1024
    float* Bs  = (float*)(smem + 155904);           // 128

    const int tid  = threadIdx.x;
    const int wgid = blockIdx.x;
    const int layer = wgid >> 7;
    const int lwg  = wgid & 127;
    const int bg   = (lwg >> 2) & 1;
    const int ug   = ((lwg >> 3) << 2) | (lwg & 3);
    const int b0   = bg * NBAT;
    const int u0   = ug * 8;
    const int lane = tid & 63;
    const int wid  = tid >> 6;
    const int col  = lane & 15;
    const int kg   = lane >> 4;
    const int rt   = (wid >> 1) & 1;
    const int bt   = wid & 1;
    const int kh   = wid >> 2;

    u16t* hbhi = (u16t*)(ws + (layer ? WS_HB1HI : WS_HB0HI));
    u16t* hblo = (u16t*)(ws + (layer ? WS_HB1LO : WS_HB0LO));
    int* slots_self = (int*)(ws + (layer ? WS_SLOT1 : WS_SLOT0)) + bg * 256;
    int* slots_l0   = (int*)(ws + WS_SLOT0) + bg * 256;
    int* gdone      = (int*)(ws + WS_GDONE) + bg * 256;
    int* xpd        = (int*)(ws + WS_XPD)   + bg * 256;
    const float* bsum = (const float*)(ws + (layer ? WS_BSUM1 : WS_BSUM0));
    u32t* hist = (u32t*)(ws + WS_HIST);
    float* xpregion = (float*)(ws + (layer ? WS_XP1 : WS_XP0));
    float* xp_self = xpregion + (size_t)lwg * 16384;

    // ---- one-time init ----
    if (tid < 256) Cs[tid] = 0.f;
    if (tid < 32) {
        int grow = (tid >> 3) * HID + u0 + (tid & 7);
        Bs[tid] = bsum[grow];
    }
    if (layer == 0) {
        for (int s = tid; s < 32 * 24; s += 512) {     // W_ih0 slice (96 = 24 u64)
            int rl = s / 24, sl = s % 24;
            int grow = (rl >> 3) * HID + u0 + (rl & 7);
            u64t v  = *((const u64t*)((u16t*)(ws + WS_PIH0HI) + (size_t)grow * 96) + sl);
            u64t v2 = *((const u64t*)((u16t*)(ws + WS_PIH0LO) + (size_t)grow * 96) + sl);
            *((u64t*)(XWhi + (size_t)rl * XPI) + sl) = v;
            *((u64t*)(XWlo + (size_t)rl * XPI) + sl) = v2;
        }
    }
    __syncthreads();

    if (layer == 0) {
        // =========== LAYER 0 ===========
        for (int c = 0; c < NCHUNK; ++c) {
            // ---- xp0 chunk GEMM: D[512 m][32 rows] = x * W_ih0^T (+bias) ----
            {
                f32x4 acc[4][2];
#pragma unroll
                for (int m4 = 0; m4 < 4; ++m4)
#pragma unroll
                    for (int nt = 0; nt < 2; ++nt)
                        acc[m4][nt] = (f32x4){0.f, 0.f, 0.f, 0.f};
#pragma unroll
                for (int kt = 0; kt < 3; ++kt) {
                    int k0 = kt * 32 + kg * 8;
                    s16x8 ah0 = *(const s16x8*)(XWhi + (size_t)(col) * XPI + k0);
                    s16x8 al0 = *(const s16x8*)(XWlo + (size_t)(col) * XPI + k0);
                    s16x8 ah1 = *(const s16x8*)(XWhi + (size_t)(16 + col) * XPI + k0);
                    s16x8 al1 = *(const s16x8*)(XWlo + (size_t)(16 + col) * XPI + k0);
#pragma unroll
                    for (int m4 = 0; m4 < 4; ++m4) {
                        int bb = wid * 4 + m4;             // local batch 0..31; col = tl
                        float xv[8];
                        if (kt < 2) {
                            const float* pr = prim + ((size_t)(b0 + bb) * SEQ + c * CT + col) * DPRIM + k0;
                            float4 v0 = *(const float4*)pr;
                            float4 v1 = *(const float4*)(pr + 4);
                            xv[0] = v0.x; xv[1] = v0.y; xv[2] = v0.z; xv[3] = v0.w;
                            xv[4] = v1.x; xv[5] = v1.y; xv[6] = v1.z; xv[7] = v1.w;
                        } else {
                            const float* ax = aux + (size_t)(b0 + bb) * DAUX + kg * 8;
                            float4 v0 = *(const float4*)ax;
                            float4 v1 = *(const float4*)(ax + 4);
                            xv[0] = v0.x; xv[1] = v0.y; xv[2] = v0.z; xv[3] = v0.w;
                            xv[4] = v1.x; xv[5] = v1.y; xv[6] = v1.z; xv[7] = v1.w;
                        }
                        u16t hh[8], ll[8];
#pragma unroll
                        for (int j = 0; j < 8; ++j) split2(xv[j], &hh[j], &ll[j]);
                        s16x8 bhv, blv;
#pragma unroll
                        for (int j = 0; j < 8; ++j) { bhv[j] = (short)hh[j]; blv[j] = (short)ll[j]; }
                        acc[m4][0] = MFMA16(ah0, bhv, acc[m4][0]);
                        acc[m4][0] = MFMA16(ah0, blv, acc[m4][0]);
                        acc[m4][0] = MFMA16(al0, bhv, acc[m4][0]);
                        acc[m4][1] = MFMA16(ah1, bhv, acc[m4][1]);
                        acc[m4][1] = MFMA16(ah1, blv, acc[m4][1]);
                        acc[m4][1] = MFMA16(al1, bhv, acc[m4][1]);
                    }
                }
#pragma unroll
                for (int m4 = 0; m4 < 4; ++m4) {
                    int m = (wid * 4 + m4) * 16 + col;
#pragma unroll
                    for (int nt = 0; nt < 2; ++nt)
#pragma unroll
                        for (int j = 0; j < 4; ++j) {
                            int gr = nt * 16 + kg * 4 + j;
                            xp_self[(size_t)m * 32 + gr] = acc[m4][nt][j] + Bs[gr];
                        }
                }
            }
            // ---- A-fragments (Whh0) into registers, off critical path ----
            s16x8 ahf[8], alf[8];
            load_afrag((const u16t*)(ws + WS_PHH0HI), (const u16t*)(ws + WS_PHH0LO),
                       u0, col, kg, rt, kh, ahf, alf);
            // ---- ring backpressure: layer1 must have staged hist chunk c-2 ----
            if (c >= 2) {
                if (tid < 64) {
                    while (true) {
                        int v = ld_slot(gdone + tid * 4);
                        if (__all(v >= c - 1)) break;
                        __builtin_amdgcn_s_sleep(1);
                    }
                }
            }
            __syncthreads();
            for (int tl = 0; tl < CT; ++tl)
                do_step(c * CT + tl, c, tl, tid, col, kg, rt, bt, kh, b0, u0, ug,
                        ahf, alf, Ps, Cs, hbhi, hblo, slots_self,
                        xp_self, false, hist);
        }
    } else {
        // =========== LAYER 1 ===========
        const int gm = ug >> 3, gn = ug & 7;
        for (int c = 0; c < NCHUNK; ++c) {
            // gate: layer0 finished chunk c
            if (tid < 64) {
                while (true) {
                    int v = ld_slot(slots_l0 + tid * 4);
                    if (__all(v >= (c + 1) * CT)) break;
                    __builtin_amdgcn_s_sleep(1);
                }
            }
            __syncthreads();
            // stage B-tile (64 m-rows x 512 k) from hist ring[c&1], unpack hi/lo
            {
                int i = tid >> 3, j = tid & 7;
                int m = gm * 64 + i;
                int gb = b0 + (m >> 4), tl2 = m & 15;
                const u64t* src = (const u64t*)(hist + ((size_t)((c & 1) * BATCH + gb) * CT + tl2) * HID);
                u64t* dh = (u64t*)(Bthi + (size_t)i * WP);
                u64t* dl = (u64t*)(Btlo + (size_t)i * WP);
#pragma unroll
                for (int q = 0; q < 16; ++q) {
                    int g = q * 8 + j;
                    u64t w0 = ld_coh64(src + g * 2);
                    u64t w1 = ld_coh64(src + g * 2 + 1);
                    u32t e0 = (u32t)w0, e1 = (u32t)(w0 >> 32);
                    u32t e2 = (u32t)w1, e3 = (u32t)(w1 >> 32);
                    dh[g] = (u64t)(e0 >> 16) | ((u64t)(e1 >> 16) << 16) |
                            ((u64t)(e2 >> 16) << 32) | ((u64t)(e3 >> 16) << 48);
                    dl[g] = (u64t)(e0 & 0xffffu) | ((u64t)(e1 & 0xffffu) << 16) |
                            ((u64t)(e2 & 0xffffu) << 32) | ((u64t)(e3 & 0xffffu) << 48);
                }
            }
            __syncthreads();
            if (tid == 0) st_slot(gdone + ug * 4, c + 1);   // hist ring slot consumed
            // ---- 2D-tiled xp1 GEMM: (gm:64m) x (gn:256n), K=512, bf16x3 ----
            {
                const u16t* pih = (const u16t*)(ws + WS_PIH1HI);
                const u16t* pil = (const u16t*)(ws + WS_PIH1LO);
                int Rb0 = gn * 256 + (wid * 2) * 16 + col;
                int Rb1 = Rb0 + 16;
                int g0 = ((Rb0 >> 3) & 3) * HID + (Rb0 >> 5) * 8 + (Rb0 & 7);
                int g1 = ((Rb1 >> 3) & 3) * HID + (Rb1 >> 5) * 8 + (Rb1 & 7);
                const u16t* a0h = pih + (size_t)g0 * HID;
                const u16t* a0l = pil + (size_t)g0 * HID;
                const u16t* a1h = pih + (size_t)g1 * HID;
                const u16t* a1l = pil + (size_t)g1 * HID;
                float biasv[2][4];
#pragma unroll
                for (int nt = 0; nt < 2; ++nt)
#pragma unroll
                    for (int j = 0; j < 4; ++j) {
                        int R = gn * 256 + (wid * 2 + nt) * 16 + kg * 4 + j;
                        biasv[nt][j] = bsum[((R >> 3) & 3) * HID + (R >> 5) * 8 + (R & 7)];
                    }
                f32x4 acc[4][2];
#pragma unroll
                for (int mt = 0; mt < 4; ++mt)
#pragma unroll
                    for (int nt = 0; nt < 2; ++nt)
                        acc[mt][nt] = (f32x4){0.f, 0.f, 0.f, 0.f};
                for (int kt = 0; kt < 16; ++kt) {
                    int k0 = kt * 32 + kg * 8;
                    s16x8 ah0 = *(const s16x8*)(a0h + k0), al0 = *(const s16x8*)(a0l + k0);
                    s16x8 ah1 = *(const s16x8*)(a1h + k0), al1 = *(const s16x8*)(a1l + k0);
#pragma unroll
                    for (int mt = 0; mt < 4; ++mt) {
                        const u16t* bth = Bthi + (size_t)(mt * 16 + col) * WP;
                        const u16t* btl = Btlo + (size_t)(mt * 16 + col) * WP;
                        s16x8 bhv = *(const s16x8*)(bth + k0), blv = *(const s16x8*)(btl + k0);
                        acc[mt][0] = MFMA16(ah0, bhv, acc[mt][0]);
                        acc[mt][0] = MFMA16(ah0, blv, acc[mt][0]);
                        acc[mt][0] = MFMA16(al0, bhv, acc[mt][0]);
                        acc[mt][1] = MFMA16(ah1, bhv, acc[mt][1]);
                        acc[mt][1] = MFMA16(ah1, blv, acc[mt][1]);
                        acc[mt][1] = MFMA16(al1, bhv, acc[mt][1]);
                    }
                }
#pragma unroll
                for (int mt = 0; mt < 4; ++mt)
#pragma unroll
                    for (int nt = 0; nt < 2; ++nt)
#pragma unroll
                        for (int j = 0; j < 4; ++j) {
                            int m = gm * 64 + mt * 16 + col;
                            int R = gn * 256 + (wid * 2 + nt) * 16 + kg * 4 + j;
                            int ugt = R >> 5, rl = R & 31;
                            int lwgt = ((ugt >> 2) << 3) | (bg << 2) | (ugt & 3);
                            st_cohf(xpregion + (size_t)lwgt * 16384 + (size_t)m * 32 + rl,
                                    acc[mt][nt][j] + biasv[nt][j]);
                        }
            }
            __syncthreads();                        // xp sc1 stores drained
            if (tid == 0) st_slot(xpd + ug * 4, c + 1);
            // ---- A-fragments (Whh1) into registers, overlaps the xpd wait ----
            s16x8 ahf[8], alf[8];
            load_afrag((const u16t*)(ws + WS_PHH1HI), (const u16t*)(ws + WS_PHH1LO),
                       u0, col, kg, rt, kh, ahf, alf);
            if (tid < 64) {
                while (true) {
                    int v = ld_slot(xpd + tid * 4);
                    if (__all(v >= c + 1)) break;
                    __builtin_amdgcn_s_sleep(1);
                }
            }
            __syncthreads();
            for (int tl = 0; tl < CT; ++tl)
                do_step(c * CT + tl, c, tl, tid, col, kg, rt, bt, kh, b0, u0, ug,
                        ahf, alf, Ps, Cs, hbhi, hblo, slots_self,
                        xp_self, true, nullptr);
        }
    }
}

// =====================================================================
// output projection: reconstruct h_last f32 from hi/lo planes (parity 1)
// =====================================================================
__global__ void outproj_kernel(const char* __restrict__ ws, const float* __restrict__ bout,
                               float* __restrict__ out)
{
    __shared__ float hs[HID];
    int b = blockIdx.x;
    const u16t* hh = (const u16t*)(ws + WS_HB1HI) + (size_t)(BATCH + b) * HID;
    const u16t* hl = (const u16t*)(ws + WS_HB1LO) + (size_t)(BATCH + b) * HID;
    for (int i = threadIdx.x; i < HID; i += 128)
        hs[i] = __uint_as_float((u32t)hh[i] << 16) + __uint_as_float((u32t)hl[i] << 16);
    __syncthreads();
    int o = threadIdx.x;
    const float* Wot = (const float*)(ws + WS_WOT);
    float acc = bout[o];
#pragma unroll 8
    for (int k = 0; k < HID; ++k) acc = fmaf(hs[k], Wot[k * 128 + o], acc);
    out[b * 128 + o] = acc;
}

// =====================================================================
extern "C" void kernel_launch(void* const* d_in, const int* in_sizes, int n_in,
                              void* d_out, int out_size, void* d_ws, size_t ws_size,
                              hipStream_t stream)
{
    (void)in_sizes; (void)n_in; (void)out_size; (void)ws_size;
    const float* prim = (const float*)d_in[0];
    const float* aux  = (const float*)d_in[1];
    const float* Wih0 = (const float*)d_in[2];
    const float* Whh0 = (const float*)d_in[3];
    const float* bih0 = (const float*)d_in[4];
    const float* bhh0 = (const float*)d_in[5];
    const float* Wih1 = (const float*)d_in[6];
    const float* Whh1 = (const float*)d_in[7];
    const float* bih1 = (const float*)d_in[8];
    const float* bhh1 = (const float*)d_in[9];
    const float* Wout = (const float*)d_in[10];
    const float* bout = (const float*)d_in[11];
    float* out = (float*)d_out;
    char* wsc  = (char*)d_ws;

    hipMemsetAsync(wsc, 0, WS_STATE_END, stream);
    prep_kernel<<<4096, 256, 0, stream>>>(Wih0, Whh0, bih0, bhh0,
                                          Wih1, Whh1, bih1, bhh1, Wout, wsc);

    void* margs[] = {(void*)&prim, (void*)&aux, (void*)&wsc};
    hipLaunchCooperativeKernel((void*)mega_kernel, dim3(256), dim3(512), margs, 0, stream);

    outproj_kernel<<<64, 128, 0, stream>>>(wsc, bout, out);
}

// Round 6
// 4544.988 us; speedup vs baseline: 1.4301x; 1.4301x over previous
//
#include <hip/hip_runtime.h>

// ---------------- problem dims ----------------
#define BATCH 64
#define SEQ   512
#define HID   512
#define DPRIM 64
#define DAUX  32
#define CT    16
#define NCHUNK 32
#define NBAT  32          // batches per WG
#define WP    520         // u16 pitch for L1 GEMM B-tile rows
#define XPI   104         // u16 pitch, 96-wide rows
#define PST   33

// ---------------- ws byte offsets ----------------
// h planes: [parity][block:64][batch:64][8] u16  (fragment-major tiles)
#define WS_HB0HI  0u
#define WS_HB0LO  131072u
#define WS_HB1HI  262144u
#define WS_HB1LO  393216u
#define WS_SLOT0  524288u     // per bg: 64 packed ints (256B); bg stride 256B
#define WS_SLOT1  526336u
#define WS_GDONE  528384u
#define WS_XPD    530432u
#define WS_STATE_END 532480u
#define WS_PHH0HI 532480u
#define WS_PHH0LO 2629632u
#define WS_PHH1HI 4726784u
#define WS_PHH1LO 6823936u
#define WS_PIH1HI 8921088u
#define WS_PIH1LO 11018240u
#define WS_PIH0HI 13115392u
#define WS_PIH0LO 13508608u
#define WS_BSUM0  13901824u
#define WS_BSUM1  13910016u
#define WS_WOT    13918208u
#define WS_HIST   14180352u   // u32[2][64][CT][512]  (hi<<16|lo packed)
#define WS_XP0    18374656u   // f32[128 wg][512 m][32]  layout [m][u*4+gate]
#define WS_XP1    26763264u

typedef short s16x8 __attribute__((ext_vector_type(8)));
typedef float f32x4 __attribute__((ext_vector_type(4)));
typedef unsigned long long u64x2 __attribute__((ext_vector_type(2)));
typedef unsigned long long u64t;
typedef unsigned int u32t;
typedef unsigned short u16t;

__device__ __forceinline__ float sigm(float x)  { return 1.f / (1.f + __expf(-x)); }
__device__ __forceinline__ float tanh_f(float x){ return 1.f - 2.f / (__expf(2.f * x) + 1.f); }
__device__ __forceinline__ u16t f2b(float f) {
    u32t u = __float_as_uint(f);
    u += 0x7fffu + ((u >> 16) & 1u);
    return (u16t)(u >> 16);
}
__device__ __forceinline__ void split2(float f, u16t* hi, u16t* lo) {
    u16t h = f2b(f);
    float r = f - __uint_as_float((u32t)h << 16);
    *hi = h; *lo = f2b(r);
}
// coherent (cross-XCD, MALL) access — proven R2-R5
__device__ __forceinline__ u64t ld_coh64(const u64t* p) {
    return __hip_atomic_load(p, __ATOMIC_RELAXED, __HIP_MEMORY_SCOPE_AGENT);
}
__device__ __forceinline__ void st_coh64w(u64t* p, u64t v) {
    __hip_atomic_store(p, v, __ATOMIC_RELAXED, __HIP_MEMORY_SCOPE_AGENT);
}
__device__ __forceinline__ void st_cohf(float* p, float v) {
    __hip_atomic_store(p, v, __ATOMIC_RELAXED, __HIP_MEMORY_SCOPE_AGENT);
}
__device__ __forceinline__ int ld_slot(const int* p) {
    return __hip_atomic_load(p, __ATOMIC_RELAXED, __HIP_MEMORY_SCOPE_AGENT);
}
__device__ __forceinline__ void st_slot(int* p, int v) {
    __hip_atomic_store(p, v, __ATOMIC_RELAXED, __HIP_MEMORY_SCOPE_AGENT);
}
#define MFMA16(a,b,c) __builtin_amdgcn_mfma_f32_16x16x32_bf16(a,b,c,0,0,0)

// per-wave recurrent-weight fragments into registers (plain cached loads)
__device__ __forceinline__ void load_afrag(const u16t* ph, const u16t* pl,
                                           int u0, int col, int kg, int rt, int kh,
                                           s16x8* ah, s16x8* al) {
    int r = rt * 16 + col;
    int grow = (r >> 3) * HID + u0 + (r & 7);
    const u16t* sh = ph + (size_t)grow * HID;
    const u16t* sl = pl + (size_t)grow * HID;
#pragma unroll
    for (int k2 = 0; k2 < 8; ++k2) {
        int ko = (kh * 8 + k2) * 32 + kg * 8;
        ah[k2] = *(const s16x8*)(sh + ko);
        al[k2] = *(const s16x8*)(sl + ko);
    }
}

// =====================================================================
// prep: split all weights to hi/lo bf16 planes; bias sums; W_out^T
// =====================================================================
__global__ void prep_kernel(const float* __restrict__ Wih0, const float* __restrict__ Whh0,
                            const float* __restrict__ bih0, const float* __restrict__ bhh0,
                            const float* __restrict__ Wih1, const float* __restrict__ Whh1,
                            const float* __restrict__ bih1, const float* __restrict__ bhh1,
                            const float* __restrict__ Wout, char* __restrict__ ws)
{
    int idx = blockIdx.x * 256 + threadIdx.x;          // 0..1048575
    u16t h, l;
    split2(Whh0[idx], &h, &l);
    ((u16t*)(ws + WS_PHH0HI))[idx] = h; ((u16t*)(ws + WS_PHH0LO))[idx] = l;
    split2(Whh1[idx], &h, &l);
    ((u16t*)(ws + WS_PHH1HI))[idx] = h; ((u16t*)(ws + WS_PHH1LO))[idx] = l;
    split2(Wih1[idx], &h, &l);
    ((u16t*)(ws + WS_PIH1HI))[idx] = h; ((u16t*)(ws + WS_PIH1LO))[idx] = l;
    if (idx < 2048 * 96) {
        split2(Wih0[idx], &h, &l);
        ((u16t*)(ws + WS_PIH0HI))[idx] = h; ((u16t*)(ws + WS_PIH0LO))[idx] = l;
    }
    if (idx < 2048) {
        ((float*)(ws + WS_BSUM0))[idx] = bih0[idx] + bhh0[idx];
        ((float*)(ws + WS_BSUM1))[idx] = bih1[idx] + bhh1[idx];
    }
    if (idx < 65536) {
        ((float*)(ws + WS_WOT))[idx] = Wout[(size_t)(idx & 127) * HID + (idx >> 7)];
    }
}

// =====================================================================
// one recurrent step: LDS-staged fragment-major h, reg-A, 8-wave K-split
// =====================================================================
__device__ __forceinline__ void do_step(
    int t, int c, int tl, int tid, int col, int kg,
    int rt, int bt, int kh,
    int b0, int u0, int ug,
    const s16x8* ahf, const s16x8* alf,
    u16t* Hti, u16t* Htl, float* Ps, float* Cs,
    u16t* hbhi, u16t* hblo, int* slots_self,
    const float* xp_self, bool coh_xq, u32t* hist_ring)
{
    const int p = t & 1;
    // xq prefetch (chunk-static), layout [m][u*4+gate] -> one 16B read
    float4 xq = {0.f, 0.f, 0.f, 0.f};
    if (tid < 256) {
        int b = tid >> 3, u = tid & 7;
        const float* xr = xp_self + (size_t)(b * CT + tl) * 32 + u * 4;
        if (coh_xq) {
            u64t w0 = ld_coh64((const u64t*)xr);
            u64t w1 = ld_coh64((const u64t*)xr + 1);
            xq.x = __uint_as_float((u32t)w0); xq.y = __uint_as_float((u32t)(w0 >> 32));
            xq.z = __uint_as_float((u32t)w1); xq.w = __uint_as_float((u32t)(w1 >> 32));
        } else {
            xq = *(const float4*)xr;
        }
    }
    // all-wave poll of 64 packed slots (one int per lane)
    {
        const int* sp = slots_self + (tid & 63);
        while (true) {
            int v = ld_slot(sp);
            if (__all(v >= t)) break;
            __builtin_amdgcn_s_sleep(2);
        }
    }
    asm volatile("" ::: "memory");      // forbid hoisting stage loads above poll
    // stage h(t-1): 4 tiles x 2 planes per thread, 16B contiguous both sides
    {
        int bl  = tid & 31;             // local batch
        int bk0 = tid >> 5;             // 0..15
        const u64t* gh = (const u64t*)hbhi;
        const u64t* gl = (const u64t*)hblo;
#pragma unroll
        for (int q = 0; q < 4; ++q) {
            int block = bk0 + q * 16;
            size_t tg = (((size_t)(p ^ 1) * 64 + block) * 64 + b0 + bl) * 2;
            u64t h0 = ld_coh64(gh + tg);
            u64t h1 = ld_coh64(gh + tg + 1);
            u64t l0 = ld_coh64(gl + tg);
            u64t l1 = ld_coh64(gl + tg + 1);
            int lt = (block * 32 + bl) * 8;
            *(u64x2*)(Hti + lt) = (u64x2){h0, h1};
            *(u64x2*)(Htl + lt) = (u64x2){l0, l1};
        }
    }
    __syncthreads();
    // MFMA: all 8 waves (rt x bt x kh), bf16x3, 2 independent chains
    {
        f32x4 a0 = {0.f, 0.f, 0.f, 0.f}, a1 = {0.f, 0.f, 0.f, 0.f};
#pragma unroll
        for (int k2 = 0; k2 < 8; ++k2) {
            int blk = kh * 32 + k2 * 4 + kg;
            const u16t* hb = Hti + ((size_t)blk * 32 + bt * 16 + col) * 8;
            const u16t* lb = Htl + ((size_t)blk * 32 + bt * 16 + col) * 8;
            s16x8 bhv = *(const s16x8*)hb;
            s16x8 blv = *(const s16x8*)lb;
            a0 = MFMA16(ahf[k2], bhv, a0);
            a1 = MFMA16(ahf[k2], blv, a1);
            a0 = MFMA16(alf[k2], bhv, a0);
        }
        a0 = a0 + a1;
#pragma unroll
        for (int j = 0; j < 4; ++j)
            Ps[((kh << 5) + rt * 16 + kg * 4 + j) * PST + bt * 16 + col] = a0[j];
    }
    __syncthreads();
    // activations + state + fragment-major coherent publish
    if (tid < 256) {
        int b = tid >> 3, u = tid & 7;
        float gi = Ps[(u)      * PST + b] + Ps[(32 + u) * PST + b] + xq.x;
        float gf = Ps[(8 + u)  * PST + b] + Ps[(40 + u) * PST + b] + xq.y;
        float gg = Ps[(16 + u) * PST + b] + Ps[(48 + u) * PST + b] + xq.z;
        float go = Ps[(24 + u) * PST + b] + Ps[(56 + u) * PST + b] + xq.w;
        float si = sigm(gi), sf = sigm(gf), so = sigm(go);
        float tg = tanh_f(gg);
        float cN = sf * Cs[tid] + si * tg;
        Cs[tid] = cN;
        float hN = so * tanh_f(cN);
        u16t hi, lo; split2(hN, &hi, &lo);
        u32t wh = (u32t)hi | (((u32t)(u16t)__shfl_xor((int)hi, 1)) << 16);
        u32t wl = (u32t)lo | (((u32t)(u16t)__shfl_xor((int)lo, 1)) << 16);
        u64t qh = (u64t)wh | ((u64t)(u32t)__shfl_xor((int)wh, 2) << 32);
        u64t ql = (u64t)wl | ((u64t)(u32t)__shfl_xor((int)wl, 2) << 32);
        size_t tg2 = (((size_t)p * 64 + ug) * 64 + b0 + b) * 2;
        if ((u & 3) == 0) {
            st_coh64w((u64t*)hbhi + tg2 + (u >> 2), qh);
            st_coh64w((u64t*)hblo + tg2 + (u >> 2), ql);
        }
        if (hist_ring) {
            u32t pk = ((u32t)hi << 16) | (u32t)lo;
            u64t qp = (u64t)pk | ((u64t)(u32t)__shfl_xor((int)pk, 1) << 32);
            if ((u & 1) == 0)
                st_coh64w((u64t*)(hist_ring +
                    ((size_t)((c & 1) * BATCH + b0 + b) * CT + tl) * HID + u0 + u), qp);
        }
    }
    __syncthreads();   // drains vmcnt: publishes globally visible
    if (tid == 0) st_slot(slots_self + ug, t + 1);
}

// =====================================================================
// mega kernel: 256 WGs resident. WG 0..127 = layer0, 128..255 = layer1.
// =====================================================================
__global__ __launch_bounds__(512, 2)
void mega_kernel(const float* __restrict__ prim, const float* __restrict__ aux,
                 char* __restrict__ ws)
{
    __shared__ __align__(16) unsigned char smem[156032];
    // union region [0,133120): steps use Hti/Htl (64KB); L1 GEMM uses Bthi/Btlo
    u16t* Hti  = (u16t*)smem;                       // 32768 [block][batch32][8]
    u16t* Htl  = (u16t*)(smem + 32768);             // 32768
    u16t* Bthi = (u16t*)smem;                       // 66560 (L1 GEMM B-tile)
    u16t* Btlo = (u16t*)(smem + 66560);             // 66560
    u16t* XWhi = (u16t*)(smem + 133120);            // 6656  (L0 W_ih tiles)
    u16t* XWlo = (u16t*)(smem + 139776);            // 6656
    float* Ps  = (float*)(smem + 146432);           // 8448  [64][PST]
    float* Cs  = (float*)(smem + 154880);           // 1024
    float* Bs  = (float*)(smem + 155904);           // 128

    const int tid  = threadIdx.x;
    const int wgid = blockIdx.x;
    const int layer = wgid >> 7;
    const int lwg  = wgid & 127;
    const int bg   = (lwg >> 2) & 1;
    const int ug   = ((lwg >> 3) << 2) | (lwg & 3);
    const int b0   = bg * NBAT;
    const int u0   = ug * 8;
    const int lane = tid & 63;
    const int wid  = tid >> 6;
    const int col  = lane & 15;
    const int kg   = lane >> 4;
    const int rt   = (wid >> 1) & 1;
    const int bt   = wid & 1;
    const int kh   = wid >> 2;

    u16t* hbhi = (u16t*)(ws + (layer ? WS_HB1HI : WS_HB0HI));
    u16t* hblo = (u16t*)(ws + (layer ? WS_HB1LO : WS_HB0LO));
    int* slots_self = (int*)(ws + (layer ? WS_SLOT1 : WS_SLOT0) + bg * 256);
    int* slots_l0   = (int*)(ws + WS_SLOT0 + bg * 256);
    int* gdone      = (int*)(ws + WS_GDONE + bg * 256);
    int* xpd        = (int*)(ws + WS_XPD   + bg * 256);
    const float* bsum = (const float*)(ws + (layer ? WS_BSUM1 : WS_BSUM0));
    u32t* hist = (u32t*)(ws + WS_HIST);
    float* xpregion = (float*)(ws + (layer ? WS_XP1 : WS_XP0));
    float* xp_self = xpregion + (size_t)lwg * 16384;

    // ---- one-time init ----
    if (tid < 256) Cs[tid] = 0.f;
    if (tid < 32) {
        int grow = (tid >> 3) * HID + u0 + (tid & 7);
        Bs[tid] = bsum[grow];
    }
    if (layer == 0) {
        for (int s = tid; s < 32 * 24; s += 512) {     // W_ih0 slice (96 = 24 u64)
            int rl = s / 24, sl = s % 24;
            int grow = (rl >> 3) * HID + u0 + (rl & 7);
            u64t v  = *((const u64t*)((u16t*)(ws + WS_PIH0HI) + (size_t)grow * 96) + sl);
            u64t v2 = *((const u64t*)((u16t*)(ws + WS_PIH0LO) + (size_t)grow * 96) + sl);
            *((u64t*)(XWhi + (size_t)rl * XPI) + sl) = v;
            *((u64t*)(XWlo + (size_t)rl * XPI) + sl) = v2;
        }
    }
    __syncthreads();

    if (layer == 0) {
        // =========== LAYER 0 ===========
        for (int c = 0; c < NCHUNK; ++c) {
            // ---- xp0 chunk GEMM: D[512 m][32 rows] = x * W_ih0^T (+bias) ----
            {
                f32x4 acc[4][2];
#pragma unroll
                for (int m4 = 0; m4 < 4; ++m4)
#pragma unroll
                    for (int nt = 0; nt < 2; ++nt)
                        acc[m4][nt] = (f32x4){0.f, 0.f, 0.f, 0.f};
#pragma unroll
                for (int kt = 0; kt < 3; ++kt) {
                    int k0 = kt * 32 + kg * 8;
                    s16x8 ah0 = *(const s16x8*)(XWhi + (size_t)(col) * XPI + k0);
                    s16x8 al0 = *(const s16x8*)(XWlo + (size_t)(col) * XPI + k0);
                    s16x8 ah1 = *(const s16x8*)(XWhi + (size_t)(16 + col) * XPI + k0);
                    s16x8 al1 = *(const s16x8*)(XWlo + (size_t)(16 + col) * XPI + k0);
#pragma unroll
                    for (int m4 = 0; m4 < 4; ++m4) {
                        int bb = wid * 4 + m4;             // local batch 0..31; col = tl
                        float xv[8];
                        if (kt < 2) {
                            const float* pr = prim + ((size_t)(b0 + bb) * SEQ + c * CT + col) * DPRIM + k0;
                            float4 v0 = *(const float4*)pr;
                            float4 v1 = *(const float4*)(pr + 4);
                            xv[0] = v0.x; xv[1] = v0.y; xv[2] = v0.z; xv[3] = v0.w;
                            xv[4] = v1.x; xv[5] = v1.y; xv[6] = v1.z; xv[7] = v1.w;
                        } else {
                            const float* ax = aux + (size_t)(b0 + bb) * DAUX + kg * 8;
                            float4 v0 = *(const float4*)ax;
                            float4 v1 = *(const float4*)(ax + 4);
                            xv[0] = v0.x; xv[1] = v0.y; xv[2] = v0.z; xv[3] = v0.w;
                            xv[4] = v1.x; xv[5] = v1.y; xv[6] = v1.z; xv[7] = v1.w;
                        }
                        u16t hh[8], ll[8];
#pragma unroll
                        for (int j = 0; j < 8; ++j) split2(xv[j], &hh[j], &ll[j]);
                        s16x8 bhv, blv;
#pragma unroll
                        for (int j = 0; j < 8; ++j) { bhv[j] = (short)hh[j]; blv[j] = (short)ll[j]; }
                        acc[m4][0] = MFMA16(ah0, bhv, acc[m4][0]);
                        acc[m4][0] = MFMA16(ah0, blv, acc[m4][0]);
                        acc[m4][0] = MFMA16(al0, bhv, acc[m4][0]);
                        acc[m4][1] = MFMA16(ah1, bhv, acc[m4][1]);
                        acc[m4][1] = MFMA16(ah1, blv, acc[m4][1]);
                        acc[m4][1] = MFMA16(al1, bhv, acc[m4][1]);
                    }
                }
#pragma unroll
                for (int m4 = 0; m4 < 4; ++m4) {
                    int m = (wid * 4 + m4) * 16 + col;
#pragma unroll
                    for (int nt = 0; nt < 2; ++nt)
#pragma unroll
                        for (int j = 0; j < 4; ++j) {
                            int gr = nt * 16 + kg * 4 + j;   // gate*8+u
                            xp_self[(size_t)m * 32 + (gr & 7) * 4 + (gr >> 3)] =
                                acc[m4][nt][j] + Bs[gr];
                        }
                }
            }
            // ---- A-fragments (Whh0) into registers, off critical path ----
            s16x8 ahf[8], alf[8];
            load_afrag((const u16t*)(ws + WS_PHH0HI), (const u16t*)(ws + WS_PHH0LO),
                       u0, col, kg, rt, kh, ahf, alf);
            // ---- ring backpressure: layer1 must have staged hist chunk c-2 ----
            if (c >= 2) {
                if (tid < 64) {
                    while (true) {
                        int v = ld_slot(gdone + tid);
                        if (__all(v >= c - 1)) break;
                        __builtin_amdgcn_s_sleep(2);
                    }
                }
            }
            __syncthreads();
            for (int tl = 0; tl < CT; ++tl)
                do_step(c * CT + tl, c, tl, tid, col, kg, rt, bt, kh, b0, u0, ug,
                        ahf, alf, Hti, Htl, Ps, Cs, hbhi, hblo, slots_self,
                        xp_self, false, hist);
        }
    } else {
        // =========== LAYER 1 ===========
        const int gm = ug >> 3, gn = ug & 7;
        for (int c = 0; c < NCHUNK; ++c) {
            // gate: layer0 finished chunk c
            if (tid < 64) {
                while (true) {
                    int v = ld_slot(slots_l0 + tid);
                    if (__all(v >= (c + 1) * CT)) break;
                    __builtin_amdgcn_s_sleep(2);
                }
            }
            __syncthreads();
            // stage B-tile (64 m-rows x 512 k) from hist ring[c&1], unpack hi/lo
            {
                int i = tid >> 3, j = tid & 7;
                int m = gm * 64 + i;
                int gb = b0 + (m >> 4), tl2 = m & 15;
                const u64t* src = (const u64t*)(hist + ((size_t)((c & 1) * BATCH + gb) * CT + tl2) * HID);
                u64t* dh = (u64t*)(Bthi + (size_t)i * WP);
                u64t* dl = (u64t*)(Btlo + (size_t)i * WP);
#pragma unroll
                for (int q = 0; q < 16; ++q) {
                    int g = q * 8 + j;
                    u64t w0 = ld_coh64(src + g * 2);
                    u64t w1 = ld_coh64(src + g * 2 + 1);
                    u32t e0 = (u32t)w0, e1 = (u32t)(w0 >> 32);
                    u32t e2 = (u32t)w1, e3 = (u32t)(w1 >> 32);
                    dh[g] = (u64t)(e0 >> 16) | ((u64t)(e1 >> 16) << 16) |
                            ((u64t)(e2 >> 16) << 32) | ((u64t)(e3 >> 16) << 48);
                    dl[g] = (u64t)(e0 & 0xffffu) | ((u64t)(e1 & 0xffffu) << 16) |
                            ((u64t)(e2 & 0xffffu) << 32) | ((u64t)(e3 & 0xffffu) << 48);
                }
            }
            __syncthreads();
            if (tid == 0) st_slot(gdone + ug, c + 1);   // hist ring slot consumed
            // ---- 2D-tiled xp1 GEMM: (gm:64m) x (gn:256n), K=512, bf16x3 ----
            {
                const u16t* pih = (const u16t*)(ws + WS_PIH1HI);
                const u16t* pil = (const u16t*)(ws + WS_PIH1LO);
                int Rb0 = gn * 256 + (wid * 2) * 16 + col;
                int Rb1 = Rb0 + 16;
                int g0 = ((Rb0 >> 3) & 3) * HID + (Rb0 >> 5) * 8 + (Rb0 & 7);
                int g1 = ((Rb1 >> 3) & 3) * HID + (Rb1 >> 5) * 8 + (Rb1 & 7);
                const u16t* a0h = pih + (size_t)g0 * HID;
                const u16t* a0l = pil + (size_t)g0 * HID;
                const u16t* a1h = pih + (size_t)g1 * HID;
                const u16t* a1l = pil + (size_t)g1 * HID;
                float biasv[2][4];
#pragma unroll
                for (int nt = 0; nt < 2; ++nt)
#pragma unroll
                    for (int j = 0; j < 4; ++j) {
                        int R = gn * 256 + (wid * 2 + nt) * 16 + kg * 4 + j;
                        biasv[nt][j] = bsum[((R >> 3) & 3) * HID + (R >> 5) * 8 + (R & 7)];
                    }
                f32x4 acc[4][2];
#pragma unroll
                for (int mt = 0; mt < 4; ++mt)
#pragma unroll
                    for (int nt = 0; nt < 2; ++nt)
                        acc[mt][nt] = (f32x4){0.f, 0.f, 0.f, 0.f};
                for (int kt = 0; kt < 16; ++kt) {
                    int k0 = kt * 32 + kg * 8;
                    s16x8 ah0 = *(const s16x8*)(a0h + k0), al0 = *(const s16x8*)(a0l + k0);
                    s16x8 ah1 = *(const s16x8*)(a1h + k0), al1 = *(const s16x8*)(a1l + k0);
#pragma unroll
                    for (int mt = 0; mt < 4; ++mt) {
                        const u16t* bth = Bthi + (size_t)(mt * 16 + col) * WP;
                        const u16t* btl = Btlo + (size_t)(mt * 16 + col) * WP;
                        s16x8 bhv = *(const s16x8*)(bth + k0), blv = *(const s16x8*)(btl + k0);
                        acc[mt][0] = MFMA16(ah0, bhv, acc[mt][0]);
                        acc[mt][0] = MFMA16(ah0, blv, acc[mt][0]);
                        acc[mt][0] = MFMA16(al0, bhv, acc[mt][0]);
                        acc[mt][1] = MFMA16(ah1, bhv, acc[mt][1]);
                        acc[mt][1] = MFMA16(ah1, blv, acc[mt][1]);
                        acc[mt][1] = MFMA16(al1, bhv, acc[mt][1]);
                    }
                }
#pragma unroll
                for (int mt = 0; mt < 4; ++mt)
#pragma unroll
                    for (int nt = 0; nt < 2; ++nt)
#pragma unroll
                        for (int j = 0; j < 4; ++j) {
                            int m = gm * 64 + mt * 16 + col;
                            int R = gn * 256 + (wid * 2 + nt) * 16 + kg * 4 + j;
                            int ugt = R >> 5, rl = R & 31;   // rl = gate*8+u
                            int lwgt = ((ugt >> 2) << 3) | (bg << 2) | (ugt & 3);
                            st_cohf(xpregion + (size_t)lwgt * 16384 + (size_t)m * 32 +
                                        (rl & 7) * 4 + (rl >> 3),
                                    acc[mt][nt][j] + biasv[nt][j]);
                        }
            }
            __syncthreads();                        // xp sc1 stores drained
            if (tid == 0) st_slot(xpd + ug, c + 1);
            // ---- A-fragments (Whh1) into registers, overlaps the xpd wait ----
            s16x8 ahf[8], alf[8];
            load_afrag((const u16t*)(ws + WS_PHH1HI), (const u16t*)(ws + WS_PHH1LO),
                       u0, col, kg, rt, kh, ahf, alf);
            if (tid < 64) {
                while (true) {
                    int v = ld_slot(xpd + tid);
                    if (__all(v >= c + 1)) break;
                    __builtin_amdgcn_s_sleep(2);
                }
            }
            __syncthreads();
            for (int tl = 0; tl < CT; ++tl)
                do_step(c * CT + tl, c, tl, tid, col, kg, rt, bt, kh, b0, u0, ug,
                        ahf, alf, Hti, Htl, Ps, Cs, hbhi, hblo, slots_self,
                        xp_self, true, nullptr);
        }
    }
}

// =====================================================================
// output projection: reconstruct h_last f32 from tiled planes (parity 1)
// =====================================================================
__global__ void outproj_kernel(const char* __restrict__ ws, const float* __restrict__ bout,
                               float* __restrict__ out)
{
    __shared__ float hs[HID];
    int b = blockIdx.x;
    const u16t* ph = (const u16t*)(ws + WS_HB1HI);
    const u16t* pl = (const u16t*)(ws + WS_HB1LO);
    for (int i = threadIdx.x; i < HID; i += 128) {
        size_t e = (((size_t)64 + (i >> 3)) * 64 + b) * 8 + (i & 7);
        hs[i] = __uint_as_float((u32t)ph[e] << 16) + __uint_as_float((u32t)pl[e] << 16);
    }
    __syncthreads();
    int o = threadIdx.x;
    const float* Wot = (const float*)(ws + WS_WOT);
    float acc = bout[o];
#pragma unroll 8
    for (int k = 0; k < HID; ++k) acc = fmaf(hs[k], Wot[k * 128 + o], acc);
    out[b * 128 + o] = acc;
}

// =====================================================================
extern "C" void kernel_launch(void* const* d_in, const int* in_sizes, int n_in,
                              void* d_out, int out_size, void* d_ws, size_t ws_size,
                              hipStream_t stream)
{
    (void)in_sizes; (void)n_in; (void)out_size; (void)ws_size;
    const float* prim = (const float*)d_in[0];
    const float* aux  = (const float*)d_in[1];
    const float* Wih0 = (const float*)d_in[2];
    const float* Whh0 = (const float*)d_in[3];
    const float* bih0 = (const float*)d_in[4];
    const float* bhh0 = (const float*)d_in[5];
    const float* Wih1 = (const float*)d_in[6];
    const float* Whh1 = (const float*)d_in[7];
    const float* bih1 = (const float*)d_in[8];
    const float* bhh1 = (const float*)d_in[9];
    const float* Wout = (const float*)d_in[10];
    const float* bout = (const float*)d_in[11];
    float* out = (float*)d_out;
    char* wsc  = (char*)d_ws;

    hipMemsetAsync(wsc, 0, WS_STATE_END, stream);
    prep_kernel<<<4096, 256, 0, stream>>>(Wih0, Whh0, bih0, bhh0,
                                          Wih1, Whh1, bih1, bhh1, Wout, wsc);

    void* margs[] = {(void*)&prim, (void*)&aux, (void*)&wsc};
    hipLaunchCooperativeKernel((void*)mega_kernel, dim3(256), dim3(512), margs, 0, stream);

    outproj_kernel<<<64, 128, 0, stream>>>(wsc, bout, out);
}

// Round 8
// 3303.143 us; speedup vs baseline: 1.9677x; 1.3760x over previous
//
#include <hip/hip_runtime.h>

// ---------------- problem dims ----------------
#define BATCH 64
#define SEQ   512
#define HID   512
#define DPRIM 64
#define DAUX  32
#define DIN   96
#define CT    16
#define NCHUNK 32
#define NBAT  32          // batches per WG
#define WP    520         // u16 pitch for L1 GEMM B-tile rows
#define XPI   104         // u16 pitch, 96-wide rows
#define PST   33

// ---------------- ws byte offsets ----------------
// h planes: [parity][block:64][batch:64][8] u16 (fragment-major tiles)
#define WS_HB0HI  0u
#define WS_HB0LO  131072u
#define WS_HB1HI  262144u
#define WS_HB1LO  393216u
#define WS_SLOT0  524288u     // per bg: 64 slots x 16B stride (1024B); bg stride 1024B
#define WS_SLOT1  526336u
#define WS_GDONE  528384u
#define WS_XPD    530432u
#define WS_STATE_END 532480u
#define WS_PHH0HI 532480u
#define WS_PHH0LO 2629632u
#define WS_PHH1HI 4726784u
#define WS_PHH1LO 6823936u
#define WS_PIH1HI 8921088u
#define WS_PIH1LO 11018240u
#define WS_PIH0HI 13115392u
#define WS_PIH0LO 13508608u
#define WS_BSUM0  13901824u
#define WS_BSUM1  13910016u
#define WS_WOT    13918208u
#define WS_HIST   14180352u   // u32[2][64][CT][512]  (hi<<16|lo packed)
#define WS_XP0    18374656u   // f32[128 wg][512 m][32]  layout [m][u*4+gate]
#define WS_XP1    26763264u

typedef short s16x8 __attribute__((ext_vector_type(8)));
typedef float f32x4 __attribute__((ext_vector_type(4)));
typedef unsigned long long u64x2 __attribute__((ext_vector_type(2)));
typedef unsigned long long u64t;
typedef unsigned int u32t;
typedef unsigned short u16t;

__device__ __forceinline__ float sigm(float x)  { return 1.f / (1.f + __expf(-x)); }
__device__ __forceinline__ float tanh_f(float x){ return 1.f - 2.f / (__expf(2.f * x) + 1.f); }
__device__ __forceinline__ u16t f2b(float f) {
    u32t u = __float_as_uint(f);
    u += 0x7fffu + ((u >> 16) & 1u);
    return (u16t)(u >> 16);
}
__device__ __forceinline__ void split2(float f, u16t* hi, u16t* lo) {
    u16t h = f2b(f);
    float r = f - __uint_as_float((u32t)h << 16);
    *hi = h; *lo = f2b(r);
}
// coherent (cross-XCD, MALL) access — proven R2-R6
__device__ __forceinline__ u64t ld_coh64(const u64t* p) {
    return __hip_atomic_load(p, __ATOMIC_RELAXED, __HIP_MEMORY_SCOPE_AGENT);
}
__device__ __forceinline__ void st_coh64w(u64t* p, u64t v) {
    __hip_atomic_store(p, v, __ATOMIC_RELAXED, __HIP_MEMORY_SCOPE_AGENT);
}
__device__ __forceinline__ void st_cohf(float* p, float v) {
    __hip_atomic_store(p, v, __ATOMIC_RELAXED, __HIP_MEMORY_SCOPE_AGENT);
}
__device__ __forceinline__ int ld_slot(const int* p) {
    return __hip_atomic_load(p, __ATOMIC_RELAXED, __HIP_MEMORY_SCOPE_AGENT);
}
__device__ __forceinline__ void st_slot(int* p, int v) {
    __hip_atomic_store(p, v, __ATOMIC_RELAXED, __HIP_MEMORY_SCOPE_AGENT);
}
#define MFMA16(a,b,c) __builtin_amdgcn_mfma_f32_16x16x32_bf16(a,b,c,0,0,0)

// per-wave recurrent-weight fragments into registers (plain cached loads)
__device__ __forceinline__ void load_afrag(const u16t* ph, const u16t* pl,
                                           int u0, int col, int kg, int rt, int kh,
                                           s16x8* ah, s16x8* al) {
    int r = rt * 16 + col;
    int grow = (r >> 3) * HID + u0 + (r & 7);
    const u16t* sh = ph + (size_t)grow * HID;
    const u16t* sl = pl + (size_t)grow * HID;
#pragma unroll
    for (int k2 = 0; k2 < 8; ++k2) {
        int ko = (kh * 8 + k2) * 32 + kg * 8;
        ah[k2] = *(const s16x8*)(sh + ko);
        al[k2] = *(const s16x8*)(sl + ko);
    }
}

// =====================================================================
// prep: split all weights to hi/lo bf16 planes; bias sums; W_out^T
// =====================================================================
__global__ void prep_kernel(const float* __restrict__ Wih0, const float* __restrict__ Whh0,
                            const float* __restrict__ bih0, const float* __restrict__ bhh0,
                            const float* __restrict__ Wih1, const float* __restrict__ Whh1,
                            const float* __restrict__ bih1, const float* __restrict__ bhh1,
                            const float* __restrict__ Wout, char* __restrict__ ws)
{
    int idx = blockIdx.x * 256 + threadIdx.x;          // 0..1048575
    u16t h, l;
    split2(Whh0[idx], &h, &l);
    ((u16t*)(ws + WS_PHH0HI))[idx] = h; ((u16t*)(ws + WS_PHH0LO))[idx] = l;
    split2(Whh1[idx], &h, &l);
    ((u16t*)(ws + WS_PHH1HI))[idx] = h; ((u16t*)(ws + WS_PHH1LO))[idx] = l;
    split2(Wih1[idx], &h, &l);
    ((u16t*)(ws + WS_PIH1HI))[idx] = h; ((u16t*)(ws + WS_PIH1LO))[idx] = l;
    if (idx < 2048 * 96) {
        split2(Wih0[idx], &h, &l);
        ((u16t*)(ws + WS_PIH0HI))[idx] = h; ((u16t*)(ws + WS_PIH0LO))[idx] = l;
    }
    if (idx < 2048) {
        ((float*)(ws + WS_BSUM0))[idx] = bih0[idx] + bhh0[idx];
        ((float*)(ws + WS_BSUM1))[idx] = bih1[idx] + bhh1[idx];
    }
    if (idx < 65536) {
        ((float*)(ws + WS_WOT))[idx] = Wout[(size_t)(idx & 127) * HID + (idx >> 7)];
    }
}

// =====================================================================
// one recurrent step: LDS-staged fragment-major h, reg-A, 8-wave K-split.
// Poll: wave 0 only (64 pollers), 16B-stride slots — R4-proven discipline.
// =====================================================================
__device__ __forceinline__ void do_step(
    int t, int c, int tl, int tid, int col, int kg,
    int rt, int bt, int kh,
    int b0, int u0, int ug,
    const s16x8* ahf, const s16x8* alf,
    u16t* Hti, u16t* Htl, float* Ps, float* Cs,
    u16t* hbhi, u16t* hblo, int* slots_self,
    const float* xp_self, bool coh_xq, u32t* hist_ring)
{
    const int p = t & 1;
    // xq prefetch (chunk-static), layout [m][u*4+gate] -> one 16B read
    float4 xq = {0.f, 0.f, 0.f, 0.f};
    if (tid < 256) {
        int b = tid >> 3, u = tid & 7;
        const float* xr = xp_self + (size_t)(b * CT + tl) * 32 + u * 4;
        if (coh_xq) {
            u64t w0 = ld_coh64((const u64t*)xr);
            u64t w1 = ld_coh64((const u64t*)xr + 1);
            xq.x = __uint_as_float((u32t)w0); xq.y = __uint_as_float((u32t)(w0 >> 32));
            xq.z = __uint_as_float((u32t)w1); xq.w = __uint_as_float((u32t)(w1 >> 32));
        } else {
            xq = *(const float4*)xr;
        }
    }
    // wave-0 poll of 64 slots at 16B stride (R4 discipline)
    if (tid < 64) {
        const int* sp = slots_self + tid * 4;
        while (true) {
            int v = ld_slot(sp);
            if (__all(v >= t)) break;
            __builtin_amdgcn_s_sleep(2);
        }
    }
    __syncthreads();
    asm volatile("" ::: "memory");      // forbid hoisting stage loads above poll
    // stage h(t-1): 4 tiles x 2 planes per thread, 16B contiguous both sides
    {
        int bl  = tid & 31;             // local batch
        int bk0 = tid >> 5;             // 0..15
        const u64t* gh = (const u64t*)hbhi;
        const u64t* gl = (const u64t*)hblo;
#pragma unroll
        for (int q = 0; q < 4; ++q) {
            int block = bk0 + q * 16;
            size_t tg = (((size_t)(p ^ 1) * 64 + block) * 64 + b0 + bl) * 2;
            u64t h0 = ld_coh64(gh + tg);
            u64t h1 = ld_coh64(gh + tg + 1);
            u64t l0 = ld_coh64(gl + tg);
            u64t l1 = ld_coh64(gl + tg + 1);
            int lt = (block * 32 + bl) * 8;
            *(u64x2*)(Hti + lt) = (u64x2){h0, h1};
            *(u64x2*)(Htl + lt) = (u64x2){l0, l1};
        }
    }
    __syncthreads();
    // MFMA: all 8 waves (rt x bt x kh), bf16x3, 2 independent chains
    {
        f32x4 a0 = {0.f, 0.f, 0.f, 0.f}, a1 = {0.f, 0.f, 0.f, 0.f};
#pragma unroll
        for (int k2 = 0; k2 < 8; ++k2) {
            int blk = kh * 32 + k2 * 4 + kg;
            const u16t* hb = Hti + ((size_t)blk * 32 + bt * 16 + col) * 8;
            const u16t* lb = Htl + ((size_t)blk * 32 + bt * 16 + col) * 8;
            s16x8 bhv = *(const s16x8*)hb;
            s16x8 blv = *(const s16x8*)lb;
            a0 = MFMA16(ahf[k2], bhv, a0);
            a1 = MFMA16(ahf[k2], blv, a1);
            a0 = MFMA16(alf[k2], bhv, a0);
        }
        a0 = a0 + a1;
#pragma unroll
        for (int j = 0; j < 4; ++j)
            Ps[((kh << 5) + rt * 16 + kg * 4 + j) * PST + bt * 16 + col] = a0[j];
    }
    __syncthreads();
    // activations + state + fragment-major coherent publish
    if (tid < 256) {
        int b = tid >> 3, u = tid & 7;
        float gi = Ps[(u)      * PST + b] + Ps[(32 + u) * PST + b] + xq.x;
        float gf = Ps[(8 + u)  * PST + b] + Ps[(40 + u) * PST + b] + xq.y;
        float gg = Ps[(16 + u) * PST + b] + Ps[(48 + u) * PST + b] + xq.z;
        float go = Ps[(24 + u) * PST + b] + Ps[(56 + u) * PST + b] + xq.w;
        float si = sigm(gi), sf = sigm(gf), so = sigm(go);
        float tg = tanh_f(gg);
        float cN = sf * Cs[tid] + si * tg;
        Cs[tid] = cN;
        float hN = so * tanh_f(cN);
        u16t hi, lo; split2(hN, &hi, &lo);
        u32t wh = (u32t)hi | (((u32t)(u16t)__shfl_xor((int)hi, 1)) << 16);
        u32t wl = (u32t)lo | (((u32t)(u16t)__shfl_xor((int)lo, 1)) << 16);
        u64t qh = (u64t)wh | ((u64t)(u32t)__shfl_xor((int)wh, 2) << 32);
        u64t ql = (u64t)wl | ((u64t)(u32t)__shfl_xor((int)wl, 2) << 32);
        size_t tg2 = (((size_t)p * 64 + ug) * 64 + b0 + b) * 2;
        if ((u & 3) == 0) {
            st_coh64w((u64t*)hbhi + tg2 + (u >> 2), qh);
            st_coh64w((u64t*)hblo + tg2 + (u >> 2), ql);
        }
        if (hist_ring) {
            u32t pk = ((u32t)hi << 16) | (u32t)lo;
            u64t qp = (u64t)pk | ((u64t)(u32t)__shfl_xor((int)pk, 1) << 32);
            if ((u & 1) == 0)
                st_coh64w((u64t*)(hist_ring +
                    ((size_t)((c & 1) * BATCH + b0 + b) * CT + tl) * HID + u0 + u), qp);
        }
    }
    __syncthreads();   // drains vmcnt: publishes globally visible
    if (tid == 0) st_slot(slots_self + ug * 4, t + 1);
}

// =====================================================================
// mega kernel: 256 WGs resident. WG 0..127 = layer0, 128..255 = layer1.
// =====================================================================
__global__ __launch_bounds__(512, 2)
void mega_kernel(const float* __restrict__ prim, const float* __restrict__ aux,
                 char* __restrict__ ws)
{
    __shared__ __align__(16) unsigned char smem[156032];
    // union region [0,133120): steps use Hti/Htl (64KB); L1 GEMM uses Bthi/Btlo
    u16t* Hti  = (u16t*)smem;                       // 32768 [block][batch32][8]
    u16t* Htl  = (u16t*)(smem + 32768);             // 32768
    u16t* Bthi = (u16t*)smem;                       // 66560 (L1 GEMM B-tile)
    u16t* Btlo = (u16t*)(smem + 66560);             // 66560
    u16t* XWhi = (u16t*)(smem + 133120);            // 6656  (L0 W_ih tiles)
    u16t* XWlo = (u16t*)(smem + 139776);            // 6656
    float* Ps  = (float*)(smem + 146432);           // 8448  [64][PST]
    float* Cs  = (float*)(smem + 154880);           // 1024
    float* Bs  = (float*)(smem + 155904);           // 128

    const int tid  = threadIdx.x;
    const int wgid = blockIdx.x;
    const int layer = wgid >> 7;
    const int lwg  = wgid & 127;
    const int bg   = (lwg >> 2) & 1;
    const int ug   = ((lwg >> 3) << 2) | (lwg & 3);
    const int b0   = bg * NBAT;
    const int u0   = ug * 8;
    const int lane = tid & 63;
    const int wid  = tid >> 6;
    const int col  = lane & 15;
    const int kg   = lane >> 4;
    const int rt   = (wid >> 1) & 1;
    const int bt   = wid & 1;
    const int kh   = wid >> 2;

    u16t* hbhi = (u16t*)(ws + (layer ? WS_HB1HI : WS_HB0HI));
    u16t* hblo = (u16t*)(ws + (layer ? WS_HB1LO : WS_HB0LO));
    int* slots_self = (int*)(ws + (layer ? WS_SLOT1 : WS_SLOT0) + bg * 1024);
    int* slots_l0   = (int*)(ws + WS_SLOT0 + bg * 1024);
    int* gdone      = (int*)(ws + WS_GDONE + bg * 1024);
    int* xpd        = (int*)(ws + WS_XPD   + bg * 1024);
    const float* bsum = (const float*)(ws + (layer ? WS_BSUM1 : WS_BSUM0));
    u32t* hist = (u32t*)(ws + WS_HIST);
    float* xpregion = (float*)(ws + (layer ? WS_XP1 : WS_XP0));
    float* xp_self = xpregion + (size_t)lwg * 16384;

    // ---- one-time init ----
    if (tid < 256) Cs[tid] = 0.f;
    if (tid < 32) {
        int grow = (tid >> 3) * HID + u0 + (tid & 7);
        Bs[tid] = bsum[grow];
    }
    if (layer == 0) {
        for (int s = tid; s < 32 * 24; s += 512) {     // W_ih0 slice (96 = 24 u64)
            int rl = s / 24, sl = s % 24;
            int grow = (rl >> 3) * HID + u0 + (rl & 7);
            u64t v  = *((const u64t*)((u16t*)(ws + WS_PIH0HI) + (size_t)grow * DIN) + sl);
            u64t v2 = *((const u64t*)((u16t*)(ws + WS_PIH0LO) + (size_t)grow * DIN) + sl);
            *((u64t*)(XWhi + (size_t)rl * XPI) + sl) = v;
            *((u64t*)(XWlo + (size_t)rl * XPI) + sl) = v2;
        }
    }
    __syncthreads();

    if (layer == 0) {
        // =========== LAYER 0 ===========
        for (int c = 0; c < NCHUNK; ++c) {
            // ---- xp0 chunk GEMM: D[512 m][32 rows] = x * W_ih0^T (+bias) ----
            {
                f32x4 acc[4][2];
#pragma unroll
                for (int m4 = 0; m4 < 4; ++m4)
#pragma unroll
                    for (int nt = 0; nt < 2; ++nt)
                        acc[m4][nt] = (f32x4){0.f, 0.f, 0.f, 0.f};
#pragma unroll
                for (int kt = 0; kt < 3; ++kt) {
                    int k0 = kt * 32 + kg * 8;
                    s16x8 ah0 = *(const s16x8*)(XWhi + (size_t)(col) * XPI + k0);
                    s16x8 al0 = *(const s16x8*)(XWlo + (size_t)(col) * XPI + k0);
                    s16x8 ah1 = *(const s16x8*)(XWhi + (size_t)(16 + col) * XPI + k0);
                    s16x8 al1 = *(const s16x8*)(XWlo + (size_t)(16 + col) * XPI + k0);
#pragma unroll
                    for (int m4 = 0; m4 < 4; ++m4) {
                        int bb = wid * 4 + m4;             // local batch 0..31; col = tl
                        float xv[8];
                        if (kt < 2) {
                            const float* pr = prim + ((size_t)(b0 + bb) * SEQ + c * CT + col) * DPRIM + k0;
                            float4 v0 = *(const float4*)pr;
                            float4 v1 = *(const float4*)(pr + 4);
                            xv[0] = v0.x; xv[1] = v0.y; xv[2] = v0.z; xv[3] = v0.w;
                            xv[4] = v1.x; xv[5] = v1.y; xv[6] = v1.z; xv[7] = v1.w;
                        } else {
                            const float* ax = aux + (size_t)(b0 + bb) * DAUX + kg * 8;
                            float4 v0 = *(const float4*)ax;
                            float4 v1 = *(const float4*)(ax + 4);
                            xv[0] = v0.x; xv[1] = v0.y; xv[2] = v0.z; xv[3] = v0.w;
                            xv[4] = v1.x; xv[5] = v1.y; xv[6] = v1.z; xv[7] = v1.w;
                        }
                        u16t hh[8], ll[8];
#pragma unroll
                        for (int j = 0; j < 8; ++j) split2(xv[j], &hh[j], &ll[j]);
                        s16x8 bhv, blv;
#pragma unroll
                        for (int j = 0; j < 8; ++j) { bhv[j] = (short)hh[j]; blv[j] = (short)ll[j]; }
                        acc[m4][0] = MFMA16(ah0, bhv, acc[m4][0]);
                        acc[m4][0] = MFMA16(ah0, blv, acc[m4][0]);
                        acc[m4][0] = MFMA16(al0, bhv, acc[m4][0]);
                        acc[m4][1] = MFMA16(ah1, bhv, acc[m4][1]);
                        acc[m4][1] = MFMA16(ah1, blv, acc[m4][1]);
                        acc[m4][1] = MFMA16(al1, bhv, acc[m4][1]);
                    }
                }
#pragma unroll
                for (int m4 = 0; m4 < 4; ++m4) {
                    int m = (wid * 4 + m4) * 16 + col;
#pragma unroll
                    for (int nt = 0; nt < 2; ++nt)
#pragma unroll
                        for (int j = 0; j < 4; ++j) {
                            int gr = nt * 16 + kg * 4 + j;   // gate*8+u
                            xp_self[(size_t)m * 32 + (gr & 7) * 4 + (gr >> 3)] =
                                acc[m4][nt][j] + Bs[gr];
                        }
                }
            }
            // ---- A-fragments (Whh0) into registers, off critical path ----
            s16x8 ahf[8], alf[8];
            load_afrag((const u16t*)(ws + WS_PHH0HI), (const u16t*)(ws + WS_PHH0LO),
                       u0, col, kg, rt, kh, ahf, alf);
            // ---- ring backpressure: layer1 must have staged hist chunk c-2 ----
            if (c >= 2) {
                if (tid < 64) {
                    while (true) {
                        int v = ld_slot(gdone + tid * 4);
                        if (__all(v >= c - 1)) break;
                        __builtin_amdgcn_s_sleep(2);
                    }
                }
            }
            __syncthreads();
            for (int tl = 0; tl < CT; ++tl)
                do_step(c * CT + tl, c, tl, tid, col, kg, rt, bt, kh, b0, u0, ug,
                        ahf, alf, Hti, Htl, Ps, Cs, hbhi, hblo, slots_self,
                        xp_self, false, hist);
        }
    } else {
        // =========== LAYER 1 ===========
        const int gm = ug >> 3, gn = ug & 7;
        for (int c = 0; c < NCHUNK; ++c) {
            // gate: layer0 finished chunk c
            if (tid < 64) {
                while (true) {
                    int v = ld_slot(slots_l0 + tid * 4);
                    if (__all(v >= (c + 1) * CT)) break;
                    __builtin_amdgcn_s_sleep(2);
                }
            }
            __syncthreads();
            // stage B-tile (64 m-rows x 512 k) from hist ring[c&1], unpack hi/lo
            {
                int i = tid >> 3, j = tid & 7;
                int m = gm * 64 + i;
                int gb = b0 + (m >> 4), tl2 = m & 15;
                const u64t* src = (const u64t*)(hist + ((size_t)((c & 1) * BATCH + gb) * CT + tl2) * HID);
                u64t* dh = (u64t*)(Bthi + (size_t)i * WP);
                u64t* dl = (u64t*)(Btlo + (size_t)i * WP);
#pragma unroll
                for (int q = 0; q < 16; ++q) {
                    int g = q * 8 + j;
                    u64t w0 = ld_coh64(src + g * 2);
                    u64t w1 = ld_coh64(src + g * 2 + 1);
                    u32t e0 = (u32t)w0, e1 = (u32t)(w0 >> 32);
                    u32t e2 = (u32t)w1, e3 = (u32t)(w1 >> 32);
                    dh[g] = (u64t)(e0 >> 16) | ((u64t)(e1 >> 16) << 16) |
                            ((u64t)(e2 >> 16) << 32) | ((u64t)(e3 >> 16) << 48);
                    dl[g] = (u64t)(e0 & 0xffffu) | ((u64t)(e1 & 0xffffu) << 16) |
                            ((u64t)(e2 & 0xffffu) << 32) | ((u64t)(e3 & 0xffffu) << 48);
                }
            }
            __syncthreads();
            if (tid == 0) st_slot(gdone + ug * 4, c + 1);   // hist ring slot consumed
            // ---- 2D-tiled xp1 GEMM: (gm:64m) x (gn:256n), K=512, bf16x3 ----
            {
                const u16t* pih = (const u16t*)(ws + WS_PIH1HI);
                const u16t* pil = (const u16t*)(ws + WS_PIH1LO);
                int Rb0 = gn * 256 + (wid * 2) * 16 + col;
                int Rb1 = Rb0 + 16;
                int g0 = ((Rb0 >> 3) & 3) * HID + (Rb0 >> 5) * 8 + (Rb0 & 7);
                int g1 = ((Rb1 >> 3) & 3) * HID + (Rb1 >> 5) * 8 + (Rb1 & 7);
                const u16t* a0h = pih + (size_t)g0 * HID;
                const u16t* a0l = pil + (size_t)g0 * HID;
                const u16t* a1h = pih + (size_t)g1 * HID;
                const u16t* a1l = pil + (size_t)g1 * HID;
                float biasv[2][4];
#pragma unroll
                for (int nt = 0; nt < 2; ++nt)
#pragma unroll
                    for (int j = 0; j < 4; ++j) {
                        int R = gn * 256 + (wid * 2 + nt) * 16 + kg * 4 + j;
                        biasv[nt][j] = bsum[((R >> 3) & 3) * HID + (R >> 5) * 8 + (R & 7)];
                    }
                f32x4 acc[4][2];
#pragma unroll
                for (int mt = 0; mt < 4; ++mt)
#pragma unroll
                    for (int nt = 0; nt < 2; ++nt)
                        acc[mt][nt] = (f32x4){0.f, 0.f, 0.f, 0.f};
                for (int kt = 0; kt < 16; ++kt) {
                    int k0 = kt * 32 + kg * 8;
                    s16x8 ah0 = *(const s16x8*)(a0h + k0), al0 = *(const s16x8*)(a0l + k0);
                    s16x8 ah1 = *(const s16x8*)(a1h + k0), al1 = *(const s16x8*)(a1l + k0);
#pragma unroll
                    for (int mt = 0; mt < 4; ++mt) {
                        const u16t* bth = Bthi + (size_t)(mt * 16 + col) * WP;
                        const u16t* btl = Btlo + (size_t)(mt * 16 + col) * WP;
                        s16x8 bhv = *(const s16x8*)(bth + k0), blv = *(const s16x8*)(btl + k0);
                        acc[mt][0] = MFMA16(ah0, bhv, acc[mt][0]);
                        acc[mt][0] = MFMA16(ah0, blv, acc[mt][0]);
                        acc[mt][0] = MFMA16(al0, bhv, acc[mt][0]);
                        acc[mt][1] = MFMA16(ah1, bhv, acc[mt][1]);
                        acc[mt][1] = MFMA16(ah1, blv, acc[mt][1]);
                        acc[mt][1] = MFMA16(al1, bhv, acc[mt][1]);
                    }
                }
#pragma unroll
                for (int mt = 0; mt < 4; ++mt)
#pragma unroll
                    for (int nt = 0; nt < 2; ++nt)
#pragma unroll
                        for (int j = 0; j < 4; ++j) {
                            int m = gm * 64 + mt * 16 + col;
                            int R = gn * 256 + (wid * 2 + nt) * 16 + kg * 4 + j;
                            int ugt = R >> 5, rl = R & 31;   // rl = gate*8+u
                            int lwgt = ((ugt >> 2) << 3) | (bg << 2) | (ugt & 3);
                            st_cohf(xpregion + (size_t)lwgt * 16384 + (size_t)m * 32 +
                                        (rl & 7) * 4 + (rl >> 3),
                                    acc[mt][nt][j] + biasv[nt][j]);
                        }
            }
            __syncthreads();                        // xp sc1 stores drained
            if (tid == 0) st_slot(xpd + ug * 4, c + 1);
            // ---- A-fragments (Whh1) into registers, overlaps the xpd wait ----
            s16x8 ahf[8], alf[8];
            load_afrag((const u16t*)(ws + WS_PHH1HI), (const u16t*)(ws + WS_PHH1LO),
                       u0, col, kg, rt, kh, ahf, alf);
            if (tid < 64) {
                while (true) {
                    int v = ld_slot(xpd + tid * 4);
                    if (__all(v >= c + 1)) break;
                    __builtin_amdgcn_s_sleep(2);
                }
            }
            __syncthreads();
            for (int tl = 0; tl < CT; ++tl)
                do_step(c * CT + tl, c, tl, tid, col, kg, rt, bt, kh, b0, u0, ug,
                        ahf, alf, Hti, Htl, Ps, Cs, hbhi, hblo, slots_self,
                        xp_self, true, nullptr);
        }
    }
}

// =====================================================================
// output projection: reconstruct h_last f32 from tiled planes (parity 1)
// =====================================================================
__global__ void outproj_kernel(const char* __restrict__ ws, const float* __restrict__ bout,
                               float* __restrict__ out)
{
    __shared__ float hs[HID];
    int b = blockIdx.x;
    const u16t* ph = (const u16t*)(ws + WS_HB1HI);
    const u16t* pl = (const u16t*)(ws + WS_HB1LO);
    for (int i = threadIdx.x; i < HID; i += 128) {
        size_t e = (((size_t)64 + (i >> 3)) * 64 + b) * 8 + (i & 7);
        hs[i] = __uint_as_float((u32t)ph[e] << 16) + __uint_as_float((u32t)pl[e] << 16);
    }
    __syncthreads();
    int o = threadIdx.x;
    const float* Wot = (const float*)(ws + WS_WOT);
    float acc = bout[o];
#pragma unroll 8
    for (int k = 0; k < HID; ++k) acc = fmaf(hs[k], Wot[k * 128 + o], acc);
    out[b * 128 + o] = acc;
}

// =====================================================================
extern "C" void kernel_launch(void* const* d_in, const int* in_sizes, int n_in,
                              void* d_out, int out_size, void* d_ws, size_t ws_size,
                              hipStream_t stream)
{
    (void)in_sizes; (void)n_in; (void)out_size; (void)ws_size;
    const float* prim = (const float*)d_in[0];
    const float* aux  = (const float*)d_in[1];
    const float* Wih0 = (const float*)d_in[2];
    const float* Whh0 = (const float*)d_in[3];
    const float* bih0 = (const float*)d_in[4];
    const float* bhh0 = (const float*)d_in[5];
    const float* Wih1 = (const float*)d_in[6];
    const float* Whh1 = (const float*)d_in[7];
    const float* bih1 = (const float*)d_in[8];
    const float* bhh1 = (const float*)d_in[9];
    const float* Wout = (const float*)d_in[10];
    const float* bout = (const float*)d_in[11];
    float* out = (float*)d_out;
    char* wsc  = (char*)d_ws;

    hipMemsetAsync(wsc, 0, WS_STATE_END, stream);
    prep_kernel<<<4096, 256, 0, stream>>>(Wih0, Whh0, bih0, bhh0,
                                          Wih1, Whh1, bih1, bhh1, Wout, wsc);

    void* margs[] = {(void*)&prim, (void*)&aux, (void*)&wsc};
    hipLaunchCooperativeKernel((void*)mega_kernel, dim3(256), dim3(512), margs, 0, stream);

    outproj_kernel<<<64, 128, 0, stream>>>(wsc, bout, out);
}